// Round 9
// baseline (169.396 us; speedup 1.0000x reference)
//
#include <hip/hip_runtime.h>

// Problem constants (reference: x = [8, 4096, 85] fp32)
constexpr int BS = 8;
constexpr int N  = 4096;
constexpr int F  = 85;
constexpr int NC = 80;          // classes = F - 5
constexpr float CONF_T = 0.65f;
constexpr float NMS_T  = 0.55f;
constexpr int SEGS = 32;        // prep segments per batch
constexpr int SEGR = 128;       // rows per segment
constexpr int SKCAP = 2048;     // per-batch valid-key cap (expected ~1430, fixed input)
constexpr int MC   = 64;        // per-(batch,class) member cap (mean ~18; P(>64) negligible)

// key = (~bits(conf))<<19 | idx<<7 | cls.  Ascending key order == (conf desc,
// idx asc) == the reference's stable argsort (idx unique -> cls bits never
// affect order; conf>0 so IEEE bits are order-monotone). conf is exactly
// recoverable: bits(conf) = ~(uint)(key>>19). Only VALID boxes get keys
// (segmented compact layout + per-segment counts).
//
// NOTE (R8 lesson): NO dynamically-indexed per-thread arrays — they demote to
// scratch (VGPR_Count=16, 10.8 MB spill traffic measured). LDS is the cache.

// ---------------- K1: prep (LDS-staged read, split argmax, segment compact) ----
__global__ __launch_bounds__(256) void prep_kernel(
        const float* __restrict__ x,
        unsigned long long* __restrict__ gkeys,   // [BS][SEGS*128] segmented
        float4* __restrict__ vbox,                // [BS*N] by original idx (valid only)
        float* __restrict__ vobj,                 // obj (valid only)
        int* __restrict__ cntblk,                 // [BS*SEGS]
        float4* __restrict__ out) {
    __shared__ __align__(16) float sx[SEGR * F];  // 43,520 B
    __shared__ float sbest2[SEGR];
    __shared__ int   sbi2[SEGR];
    __shared__ int   wq[4];
    const int tid = threadIdx.x, blk = blockIdx.x;
    const int row0 = blk * SEGR;
    // coalesced staging: row0*F*4 = blk*43520 bytes, 16B-aligned
    const float4* src = (const float4*)(x + (size_t)row0 * F);
    float4* dst = (float4*)sx;
    constexpr int NV4 = SEGR * F / 4;             // 2720
    for (int i = tid; i < NV4; i += 256) dst[i] = src[i];
    // zero this block's 128 output rows (2 float4 each, covered once per grid)
    out[(size_t)row0 * 2 + tid] = make_float4(0.f, 0.f, 0.f, 0.f);
    __syncthreads();

    // split argmax: thread (r, h) scans classes h*40..h*40+39 of row r
    const int r = tid & 127, h = tid >> 7;
    float mybest; int mybi;
    {
        const float* p = sx + r * F + 5 + h * 40;
        float best = p[0]; int bi = 0;
        #pragma unroll 8
        for (int c = 1; c < 40; ++c) {
            float v = p[c];
            if (v > best) { best = v; bi = c; }   // strict >: first max (jnp.argmax)
        }
        mybest = best; mybi = bi + h * 40;
        if (h) { sbest2[r] = best; sbi2[r] = mybi; }
    }
    __syncthreads();

    bool valid = false;
    unsigned long long key = 0;
    if (!h) {
        float b1 = sbest2[r];
        if (b1 > mybest) { mybest = b1; mybi = sbi2[r]; }  // low half wins ties
        const float* p = sx + r * F;
        float obj = p[4];
        valid = obj > CONF_T;
        const int t = row0 + r;
        if (valid) {
            float cx = p[0], cy = p[1], w = p[2], hh = p[3];
            vbox[t] = make_float4(cx - w * 0.5f, cy - hh * 0.5f,
                                  cx + w * 0.5f, cy + hh * 0.5f);
            vobj[t] = obj;
        }
        key = ((unsigned long long)(~__float_as_uint(mybest)) << 19)
            | ((unsigned long long)(unsigned)(t & (N - 1)) << 7)
            | (unsigned)mybi;
    }
    // block-local compaction (waves 2,3 contribute zero)
    const int lane = tid & 63, w = tid >> 6;
    unsigned long long mask = __ballot(valid);
    if (lane == 0) wq[w] = __popcll(mask);
    __syncthreads();
    int base = 0;
    for (int i = 0; i < w; ++i) base += wq[i];
    if (valid) {
        int slot = base + __popcll(mask & ((1ull << lane) - 1ull));
        gkeys[((size_t)(blk >> 5) << 12) + ((blk & 31) << 7) + slot] = key;
    }
    if (tid == 0) cntblk[blk] = wq[0] + wq[1];
}

// ---------------- K2: fused rank + per-(batch,class) NMS + emit ----------------
// grid (NC, BS) x 256. All 4 waves pack the batch's compact keys into LDS via a
// flat predicated loop (independent coalesced loads). Wave 0 then, LDS-based
// and wave-synchronously: ballot-collects class members, sorts them
// (lane-per-member), gathers boxes, runs greedy suppression (reference IoU,
// single-chunk inner since m<=64), computes all kept members' GLOBAL ranks in
// one chunk-outer/member-inner ballot pass (member keys live in one per-lane
// register, shfl-broadcast — no spills, no LDS in the inner loop), and writes
// kept rows straight to out[b*N+rank].
__global__ __launch_bounds__(256) void ranknms_kernel(
        const unsigned long long* __restrict__ gkeys,
        const float4* __restrict__ vbox,
        const float* __restrict__ vobj,
        const int* __restrict__ cntblk,
        float4* __restrict__ out) {
    __shared__ __align__(16) unsigned long long skeys[SKCAP];  // 16 KB
    __shared__ int scnt[SEGS];
    __shared__ int soff[SEGS];
    __shared__ int snv;
    __shared__ unsigned long long mkey[MC];     // members, collection order
    __shared__ unsigned long long smkey[MC];    // members, key-sorted
    __shared__ float4 sbox[MC];
    __shared__ float  sobj[MC];
    __shared__ unsigned char srem[MC];
    const int c = blockIdx.x, b = blockIdx.y, tid = threadIdx.x;

    // shfl prefix scan of the 32 segment counts (wave 0, lanes 0..31)
    if (tid < SEGS) {
        int v = cntblk[b * SEGS + tid];
        int xx = v;
        #pragma unroll
        for (int d = 1; d < SEGS; d <<= 1) {
            int y = __shfl_up(xx, d);
            if (tid >= d) xx += y;
        }
        scnt[tid] = v;
        soff[tid] = xx - v;                     // exclusive prefix
        if (tid == SEGS - 1) snv = xx;
    }
    __syncthreads();
    const int nv = snv < SKCAP ? snv : SKCAP;

    // flat parallel pack: slot g=(s<<7)+j -> skeys[soff[s]+j]; loads independent
    const unsigned long long* kb = gkeys + ((size_t)b << 12);
    #pragma unroll 4
    for (int g = tid; g < SEGS * SEGR; g += 256) {
        int s = g >> 7, j = g & 127;
        if (j < scnt[s]) {
            int d = soff[s] + j;
            if (d < SKCAP) skeys[d] = kb[g];
        }
    }
    __syncthreads();
    if (tid >= 64) return;                      // wave 0 only (wave-sync LDS)
    const int lane = tid;
    const int nch = (nv + 63) >> 6;

    // ballot-collect members of class c from LDS chunks (u64 stride: free alias)
    int m = 0;
    for (int ch = 0; ch < nch; ++ch) {
        int t = ch * 64 + lane;
        unsigned long long k = (t < nv) ? skeys[t] : ~0ull;  // pad cls=127 != c
        bool mem = ((int)(k & 127u) == c);
        unsigned long long mb = __ballot(mem);
        if (mem) {
            int pos = m + __popcll(mb & ((1ull << lane) - 1ull));
            if (pos < MC) mkey[pos] = k;
        }
        m += __popcll(mb);
    }
    if (m > MC) m = MC;

    // sort members by key ascending (conf desc, idx asc); lane-per-member
    if (lane < m) {
        unsigned long long myk = mkey[lane];
        int rk = 0;
        for (int j = 0; j < m; ++j) rk += (mkey[j] < myk) ? 1 : 0;
        smkey[rk] = myk;
    }
    // gather member boxes/obj (one scattered round)
    if (lane < m) {
        int idx = (int)((smkey[lane] >> 7) & (N - 1));
        int g = (b << 12) + idx;
        sbox[lane] = vbox[g];
        sobj[lane] = vobj[g];
        srem[lane] = 0;
    }

    // greedy suppression (reference IoU); m<=64 -> single-chunk inner loop
    for (int i = 0; i < m; ++i) {
        if (srem[i]) continue;                  // same LDS address: wave-uniform
        float4 bi4 = sbox[i];
        float ai = (bi4.z - bi4.x) * (bi4.w - bi4.y);
        if (lane > i && lane < m && !srem[lane]) {
            float4 bj = sbox[lane];
            float ix1 = fmaxf(bi4.x, bj.x);
            float iy1 = fmaxf(bi4.y, bj.y);
            float ix2 = fminf(bi4.z, bj.z);
            float iy2 = fminf(bi4.w, bj.w);
            float inter = fmaxf(ix2 - ix1, 0.0f) * fmaxf(iy2 - iy1, 0.0f);
            float aj = (bj.z - bj.x) * (bj.w - bj.y);
            float iou = inter / (ai + aj - inter + 1e-16f);
            if (iou > NMS_T) srem[lane] = 1;
        }
    }

    // global ranks for kept members: chunk-outer / member-inner ballot pass.
    // Lane i accumulates member i's rank; member keys shfl-broadcast from Km.
    unsigned long long Km = (lane < m) ? smkey[lane] : 0;
    int myrank = 0;
    for (int ch = 0; ch < nch; ++ch) {
        int t = ch * 64 + lane;
        unsigned long long kc = (t < nv) ? skeys[t] : ~0ull;  // pad never < Ki
        for (int i = 0; i < m; ++i) {
            if (srem[i]) continue;              // LDS broadcast: wave-uniform
            unsigned long long Ki = __shfl(Km, i);
            int cnt = __popcll(__ballot(kc < Ki));
            if (lane == i) myrank += cnt;
        }
    }

    // emit kept rows at their global rank
    for (int i = 0; i < m; ++i) {
        if (srem[i]) continue;
        int rank = __shfl(myrank, i);
        unsigned long long Ki = __shfl(Km, i);
        if (lane < 2) {
            float conf = __uint_as_float(~(unsigned)(Ki >> 19));
            float4 bq = sbox[i];
            float4 r0 = make_float4((float)b, bq.x, bq.y, bq.z);
            float4 r1 = make_float4(bq.w, sobj[i], conf, (float)c);
            float4* o = out + (size_t)((b << 12) + rank) * 2;
            o[lane] = lane ? r1 : r0;
        }
    }
}

extern "C" void kernel_launch(void* const* d_in, const int* in_sizes, int n_in,
                              void* d_out, int out_size, void* d_ws, size_t ws_size,
                              hipStream_t stream) {
    const float* x = (const float*)d_in[0];
    float4* out = (float4*)d_out;

    char* ws = (char*)d_ws;
    size_t off = 0;
    auto alloc = [&](size_t bytes) { char* p = ws + off; off += (bytes + 255) & ~255ull; return p; };
    unsigned long long* gkeys = (unsigned long long*)alloc(BS * N * 8);  // 256 KB
    float4* vbox = (float4*)alloc(BS * N * 16);                           // 512 KB
    float*  vobj = (float*)alloc(BS * N * 4);                             // 128 KB
    int*    cntblk = (int*)alloc(BS * SEGS * 4);                          // 1 KB

    prep_kernel<<<BS * N / SEGR, 256, 0, stream>>>(x, gkeys, vbox, vobj, cntblk, out);
    ranknms_kernel<<<dim3(NC, BS), 256, 0, stream>>>(gkeys, vbox, vobj, cntblk, out);
}

// Round 10
// 92.024 us; speedup vs baseline: 1.8408x; 1.8408x over previous
//
#include <hip/hip_runtime.h>

// Problem constants (reference: x = [8, 4096, 85] fp32)
constexpr int BS = 8;
constexpr int N  = 4096;
constexpr int F  = 85;
constexpr int NC = 80;          // classes = F - 5
constexpr float CONF_T = 0.65f;
constexpr float NMS_T  = 0.55f;
constexpr int MC   = 96;        // per-(batch,class) member cap (mean ~18, max ~33)
constexpr int SEGS = 32;        // prep segments per batch
constexpr int SEGR = 128;       // rows per segment

// key = (~bits(conf))<<19 | idx<<7 | cls.  Ascending key order == (conf desc,
// idx asc) == the reference's stable argsort (idx unique -> cls bits never
// affect order). Only VALID boxes get keys (segmented compact layout).
//
// Structure (measured optimum, R7 = 92.2 us):
//   prep  -> rank (parallel O(nv^2) count over ~184 blocks) -> per-class NMS.
// Fusion variants measured worse: cooperative grid.sync (R4: +30us/sync),
// per-class serial collection (R6: 90us kernel), register-array cache (R8:
// scratch spill, 10.8MB), serial rank-ballot loop (R9: 112us kernel).

// ---------------- K1: prep (LDS-staged read, split argmax, segment compact) ----
__global__ __launch_bounds__(256) void prep_kernel(
        const float* __restrict__ x,
        unsigned long long* __restrict__ gkeys,   // [BS][SEGS*128] segmented
        float4* __restrict__ vbox,                // [BS*N] by original idx (valid only)
        float2* __restrict__ vco,                 // (obj, conf)
        int* __restrict__ cntblk,                 // [BS*SEGS]
        float4* __restrict__ out) {
    __shared__ __align__(16) float sx[SEGR * F];  // 43,520 B
    __shared__ float sbest2[SEGR];
    __shared__ int   sbi2[SEGR];
    __shared__ int   wq[4];
    const int tid = threadIdx.x, blk = blockIdx.x;
    const int row0 = blk * SEGR;
    // coalesced staging: row0*F*4 = blk*43520 bytes, 16B-aligned
    const float4* src = (const float4*)(x + (size_t)row0 * F);
    float4* dst = (float4*)sx;
    constexpr int NV4 = SEGR * F / 4;             // 2720
    for (int i = tid; i < NV4; i += 256) dst[i] = src[i];
    // zero this block's 128 output rows (2 float4 each, covered once per grid)
    out[(size_t)row0 * 2 + tid] = make_float4(0.f, 0.f, 0.f, 0.f);
    __syncthreads();

    // split argmax: thread (r, h) scans classes h*40..h*40+39 of row r
    const int r = tid & 127, h = tid >> 7;
    float mybest; int mybi;
    {
        const float* p = sx + r * F + 5 + h * 40;
        float best = p[0]; int bi = 0;
        #pragma unroll 8
        for (int c = 1; c < 40; ++c) {
            float v = p[c];
            if (v > best) { best = v; bi = c; }   // strict >: first max (jnp.argmax)
        }
        mybest = best; mybi = bi + h * 40;
        if (h) { sbest2[r] = best; sbi2[r] = mybi; }
    }
    __syncthreads();

    bool valid = false;
    unsigned long long key = 0;
    if (!h) {
        float b1 = sbest2[r];
        if (b1 > mybest) { mybest = b1; mybi = sbi2[r]; }  // low half wins ties
        const float* p = sx + r * F;
        float obj = p[4];
        valid = obj > CONF_T;
        const int t = row0 + r;
        if (valid) {
            float cx = p[0], cy = p[1], w = p[2], hh = p[3];
            vbox[t] = make_float4(cx - w * 0.5f, cy - hh * 0.5f,
                                  cx + w * 0.5f, cy + hh * 0.5f);
            vco[t]  = make_float2(obj, mybest);
        }
        key = ((unsigned long long)(~__float_as_uint(mybest)) << 19)
            | ((unsigned long long)(unsigned)(t & (N - 1)) << 7)
            | (unsigned)mybi;
    }
    // block-local compaction (waves 2,3 contribute zero)
    const int lane = tid & 63, w = tid >> 6;
    unsigned long long mask = __ballot(valid);
    if (lane == 0) wq[w] = __popcll(mask);
    __syncthreads();
    int base = 0;
    for (int i = 0; i < w; ++i) base += wq[i];
    if (valid) {
        int slot = base + __popcll(mask & ((1ull << lane) - 1ull));
        gkeys[((size_t)(blk >> 5) << 12) + ((blk & 31) << 7) + slot] = key;
    }
    if (tid == 0) cntblk[blk] = wq[0] + wq[1];
}

// ---------------- K2: rank-by-count over valid keys only ----------------
// grid (64, BS) x 256. Block ranks 64 compact boxes; 4 threads each scan a
// quarter of the packed keys via b128 broadcast LDS reads. Segment pack is a
// flat predicated loop (all loads independent) using a shfl prefix scan of
// the 32 segment counts. Writes cnt[b]=nv for nms.
__global__ __launch_bounds__(256) void rank_kernel(
        const unsigned long long* __restrict__ gkeys,
        const float4* __restrict__ vbox,
        const float2* __restrict__ vco,
        const int* __restrict__ cntblk,
        float4* __restrict__ rbox,
        float2* __restrict__ rco,
        int* __restrict__ rcls,
        int* __restrict__ cnt) {
    __shared__ __align__(16) unsigned long long sk[N + 2];
    __shared__ int scnt[SEGS];
    __shared__ int soff[SEGS];
    __shared__ int snv;
    __shared__ int part[256];
    const int b = blockIdx.y, tid = threadIdx.x;
    if (tid < SEGS) {
        int v = cntblk[b * SEGS + tid];
        int xx = v;
        #pragma unroll
        for (int d = 1; d < SEGS; d <<= 1) {      // inclusive shfl scan, wave 0
            int y = __shfl_up(xx, d);
            if (tid >= d) xx += y;
        }
        scnt[tid] = v;
        soff[tid] = xx - v;                       // exclusive prefix
        if (tid == SEGS - 1) snv = xx;
    }
    __syncthreads();
    const int nv = snv;
    if (blockIdx.x == 0 && tid == 0) cnt[b] = nv;
    const int c0 = blockIdx.x * 64;
    if (c0 >= nv) return;                          // block-uniform exit

    // flat parallel pack: slot g=(s<<7)+j -> sk[soff[s]+j]; loads independent
    const unsigned long long* kb = gkeys + ((size_t)b << 12);
    #pragma unroll 4
    for (int g = tid; g < SEGS * SEGR; g += 256) {
        int s = g >> 7, j = g & 127;
        if (j < scnt[s]) sk[soff[s] + j] = kb[g];
    }
    if (tid == 0) { sk[nv] = ~0ull; sk[nv + 1] = ~0ull; }  // pair-read pad
    __syncthreads();

    const int li = tid & 63, q = tid >> 6;
    const int bi = c0 + li;
    const bool active = bi < nv;
    const unsigned long long myk = active ? sk[bi] : 0;
    const int P = (nv + 1) >> 1;                   // u64 pairs
    const int j0 = (P * q) >> 2, j1 = (P * (q + 1)) >> 2;
    const ulonglong2* skp = (const ulonglong2*)sk;
    int cr = 0;
    for (int j = j0; j < j1; ++j) {                // b128 broadcast reads
        ulonglong2 kk = skp[j];
        cr += (kk.x < myk) ? 1 : 0;
        cr += (kk.y < myk) ? 1 : 0;
    }
    part[tid] = cr;
    __syncthreads();
    if (q == 0 && active) {
        int rank = part[li] + part[li + 64] + part[li + 128] + part[li + 192];
        int idx = (int)((myk >> 7) & (N - 1));
        int s = (b << 12) + idx;
        int d = (b << 12) + rank;                  // exact stable rank
        rbox[d] = vbox[s];
        rco[d]  = vco[s];
        rcls[d] = (int)(myk & 127u);
    }
}

// ---------------- K3: per-(batch,class) greedy NMS + emit ----------------
// grid (NC, BS), one wave. 32 unrolled independent rcls chunk loads (one
// exposed latency) -> ballot compaction of member ranks; box gather in <=2
// scattered rounds; wave-synchronous greedy (reference IoU); direct row emit.
__global__ __launch_bounds__(64) void nms_kernel(
        const float4* __restrict__ rbox,
        const float2* __restrict__ rco,
        const int* __restrict__ rcls,
        const int* __restrict__ cnt,
        float4* __restrict__ out) {
    __shared__ float4 sbox[MC];
    __shared__ unsigned short srank[MC];
    __shared__ unsigned char srem[MC];
    const int c = blockIdx.x, b = blockIdx.y, lane = threadIdx.x;
    const int bN = b << 12;
    const int nv = cnt[b];
    constexpr int MAXCH = 32;                      // covers nv <= 2048 fast path

    int cv[MAXCH];
    #pragma unroll
    for (int ch = 0; ch < MAXCH; ++ch) {           // independent coalesced loads
        int rn = ch * 64 + lane;
        cv[ch] = rcls[bN + (rn < nv ? rn : 0)];    // clamped, in-bounds
    }
    int n = 0;
    #pragma unroll
    for (int ch = 0; ch < MAXCH; ++ch) {
        int rn = ch * 64 + lane;
        bool member = (rn < nv) && (cv[ch] == c);
        unsigned long long mb = __ballot(member);
        if (member) {
            int pos = n + __popcll(mb & ((1ull << lane) - 1ull));
            if (pos < MC) srank[pos] = (unsigned short)rn;
        }
        n += __popcll(mb);
    }
    for (int base = MAXCH * 64; base < nv; base += 64) {   // rare tail (nv>2048)
        int rn = base + lane;
        bool member = (rn < nv) && (rcls[bN + (rn < nv ? rn : 0)] == c);
        unsigned long long mb = __ballot(member);
        if (member) {
            int pos = n + __popcll(mb & ((1ull << lane) - 1ull));
            if (pos < MC) srank[pos] = (unsigned short)rn;
        }
        n += __popcll(mb);
    }
    if (n > MC) n = MC;
    const int m = n;

    // gather member boxes (rank order == conf-desc order), <=2 scattered rounds
    for (int i = lane; i < m; i += 64) {
        sbox[i] = rbox[bN + srank[i]];
        srem[i] = 0;
    }

    // single wave owns the LDS: wave-synchronous, no barriers needed
    for (int i = 0; i < m; ++i) {
        if (srem[i]) continue;                     // same LDS address: uniform
        float4 bi4 = sbox[i];
        float ai = (bi4.z - bi4.x) * (bi4.w - bi4.y);
        for (int j = i + 1 + lane; j < m; j += 64) {
            if (!srem[j]) {
                float4 bj = sbox[j];
                float ix1 = fmaxf(bi4.x, bj.x);
                float iy1 = fmaxf(bi4.y, bj.y);
                float ix2 = fminf(bi4.z, bj.z);
                float iy2 = fminf(bi4.w, bj.w);
                float inter = fmaxf(ix2 - ix1, 0.0f) * fmaxf(iy2 - iy1, 0.0f);
                float aj = (bj.z - bj.x) * (bj.w - bj.y);
                float iou = inter / (ai + aj - inter + 1e-16f);
                if (iou > NMS_T) srem[j] = 1;
            }
        }
    }
    for (int j = lane; j < m; j += 64) {
        if (!srem[j]) {
            int rr = srank[j];
            float4 bq = sbox[j];
            float2 oc = rco[bN + rr];
            float4* o = out + (size_t)(bN + rr) * 2;
            o[0] = make_float4((float)b, bq.x, bq.y, bq.z);
            o[1] = make_float4(bq.w, oc.x, oc.y, (float)c);
        }
    }
}

extern "C" void kernel_launch(void* const* d_in, const int* in_sizes, int n_in,
                              void* d_out, int out_size, void* d_ws, size_t ws_size,
                              hipStream_t stream) {
    const float* x = (const float*)d_in[0];
    float4* out = (float4*)d_out;

    char* ws = (char*)d_ws;
    size_t off = 0;
    auto alloc = [&](size_t bytes) { char* p = ws + off; off += (bytes + 255) & ~255ull; return p; };
    unsigned long long* gkeys = (unsigned long long*)alloc(BS * N * 8);  // 256 KB
    float4* vbox = (float4*)alloc(BS * N * 16);                           // 512 KB
    float2* vco  = (float2*)alloc(BS * N * 8);                            // 256 KB
    int*    cntblk = (int*)alloc(BS * SEGS * 4);                          // 1 KB
    float4* rbox = (float4*)alloc(BS * N * 16);                           // 512 KB
    float2* rco  = (float2*)alloc(BS * N * 8);                            // 256 KB
    int*    rcls = (int*)alloc(BS * N * 4);                               // 128 KB
    int*    cnt  = (int*)alloc(BS * 4);                                   // 32 B

    prep_kernel<<<BS * N / SEGR, 256, 0, stream>>>(x, gkeys, vbox, vco, cntblk, out);
    rank_kernel<<<dim3(64, BS), 256, 0, stream>>>(gkeys, vbox, vco, cntblk,
                                                  rbox, rco, rcls, cnt);
    nms_kernel<<<dim3(NC, BS), 64, 0, stream>>>(rbox, rco, rcls, cnt, out);
}